// Round 1
// baseline (131.423 us; speedup 1.0000x reference)
//
#include <hip/hip_runtime.h>
#include <stdint.h>

#define DATA_BITS 57
#define SHIFT_BITS 6
#define ROWS_PER_BLOCK 256
#define BLOCK 256

__global__ __launch_bounds__(BLOCK) void barrel57_kernel(
    const float* __restrict__ X, const float* __restrict__ S,
    float* __restrict__ outCur, float* __restrict__ outSticky,
    int batch)
{
    __shared__ float tile[ROWS_PER_BLOCK * DATA_BITS];     // 57 KB
    __shared__ float stile[ROWS_PER_BLOCK * SHIFT_BITS];   // 6 KB

    const int t = threadIdx.x;
    const long long blockRow0 = (long long)blockIdx.x * ROWS_PER_BLOCK;

    const long long totalX = (long long)batch * DATA_BITS;   // floats
    const long long totalS = (long long)batch * SHIFT_BITS;  // floats
    const long long xBase  = blockRow0 * DATA_BITS;          // float index, %4==0
    const long long sBase  = blockRow0 * SHIFT_BITS;         // %4==0

    // ---- cooperative coalesced float4 load of X tile -> LDS ----
    const int tileVec = ROWS_PER_BLOCK * DATA_BITS / 4;      // 3648
    const float4* Xv = (const float4*)X + (xBase >> 2);
    for (int i = t; i < tileVec; i += BLOCK) {
        if (xBase + (long long)i * 4 < totalX) {
            *(float4*)&tile[i * 4] = Xv[i];
        }
    }
    // ---- shift tile ----
    const int stileVec = ROWS_PER_BLOCK * SHIFT_BITS / 4;    // 384
    const float4* Sv = (const float4*)S + (sBase >> 2);
    for (int i = t; i < stileVec; i += BLOCK) {
        if (sBase + (long long)i * 4 < totalS) {
            *(float4*)&stile[i * 4] = Sv[i];
        }
    }
    __syncthreads();

    const long long row = blockRow0 + t;
    if (row < batch) {
        // ---- pack 57 bits (inputs are exactly 0.0f or 1.0f; bit23 of 1.0f is set) ----
        const float* r = &tile[t * DATA_BITS];
        uint32_t lo = 0, hi = 0;
        #pragma unroll
        for (int j = 0; j < 32; ++j) {
            uint32_t u = __float_as_uint(r[j]);
            lo |= ((u >> 23) & 1u) << j;
        }
        #pragma unroll
        for (int j = 32; j < DATA_BITS; ++j) {
            uint32_t u = __float_as_uint(r[j]);
            hi |= ((u >> 23) & 1u) << (j - 32);
        }
        uint64_t mask = ((uint64_t)hi << 32) | lo;

        // ---- shift amount: shift[0] has weight 32 ... shift[5] weight 1 ----
        const float* sr = &stile[t * SHIFT_BITS];
        int s = 0;
        #pragma unroll
        for (int l = 0; l < SHIFT_BITS; ++l) {
            uint32_t u = __float_as_uint(sr[l]);
            s |= (int)((u >> 23) & 1u) << (SHIFT_BITS - 1 - l);
        }

        // ---- right shift of the bit-vector == left shift of the packed mask ----
        // out[k] = X[k - s]  =>  out_mask = mask << s (s <= 63, shift defined)
        uint64_t outm = (mask << s) & ((1ULL << DATA_BITS) - 1ULL);
        // sticky = OR of bits j >= 57 - s (for s==0: mask>>57 == 0; s>=57: all bits)
        uint64_t dropped = (s >= DATA_BITS) ? mask : (mask >> (DATA_BITS - s));
        float sticky = (dropped != 0ULL) ? 1.0f : 0.0f;

        // ---- expand back to 0/1 floats into own LDS row ----
        float* w = &tile[t * DATA_BITS];
        uint32_t olo = (uint32_t)outm;
        uint32_t ohi = (uint32_t)(outm >> 32);
        #pragma unroll
        for (int k = 0; k < DATA_BITS; ++k) {
            uint32_t bit = (k < 32) ? ((olo >> k) & 1u) : ((ohi >> (k - 32)) & 1u);
            w[k] = __uint_as_float((0u - bit) & 0x3F800000u);
        }
        outSticky[row] = sticky;
    }
    __syncthreads();

    // ---- cooperative coalesced float4 store of result tile ----
    float4* Ov = (float4*)outCur + (xBase >> 2);
    for (int i = t; i < tileVec; i += BLOCK) {
        if (xBase + (long long)i * 4 < totalX) {
            Ov[i] = *(float4*)&tile[i * 4];
        }
    }
}

extern "C" void kernel_launch(void* const* d_in, const int* in_sizes, int n_in,
                              void* d_out, int out_size, void* d_ws, size_t ws_size,
                              hipStream_t stream) {
    const float* X = (const float*)d_in[0];
    const float* S = (const float*)d_in[1];
    const int batch = in_sizes[1] / SHIFT_BITS;       // 1,000,000
    float* outCur = (float*)d_out;                    // batch*57 floats
    float* outSticky = outCur + (long long)batch * DATA_BITS;  // batch floats

    const int grid = (batch + ROWS_PER_BLOCK - 1) / ROWS_PER_BLOCK;
    barrel57_kernel<<<grid, BLOCK, 0, stream>>>(X, S, outCur, outSticky, batch);
}

// Round 2
// 108.614 us; speedup vs baseline: 1.2100x; 1.2100x over previous
//
#include <hip/hip_runtime.h>
#include <stdint.h>

#define DATA_BITS 57
#define SHIFT_BITS 6
#define ROWS_PER_BLOCK 256
#define BLOCK 256

__global__ __launch_bounds__(BLOCK) void barrel57_kernel(
    const float* __restrict__ X, const float* __restrict__ S,
    float* __restrict__ outCur, float* __restrict__ outSticky,
    int batch)
{
    // Packed per-row masks (bit j = X[row][j]); built by ds_or atomics.
    __shared__ uint32_t mlo[ROWS_PER_BLOCK];
    __shared__ uint32_t mhi[ROWS_PER_BLOCK];
    __shared__ float    stile[ROWS_PER_BLOCK * SHIFT_BITS];  // 6 KB

    const int t = threadIdx.x;
    const long long blockRow0 = (long long)blockIdx.x * ROWS_PER_BLOCK;

    const long long totalX = (long long)batch * DATA_BITS;   // multiple of 4
    const long long totalS = (long long)batch * SHIFT_BITS;  // multiple of 4
    const long long xBase  = blockRow0 * DATA_BITS;
    const long long sBase  = blockRow0 * SHIFT_BITS;

    // init masks
    mlo[t] = 0u;
    mhi[t] = 0u;

    // stage shift tile (coalesced float4)
    const int stileVec = ROWS_PER_BLOCK * SHIFT_BITS / 4;    // 384
    const float4* Sv = (const float4*)S + (sBase >> 2);
    for (int i = t; i < stileVec; i += BLOCK) {
        if (sBase + (long long)i * 4 < totalS) {
            *(float4*)&stile[i * 4] = Sv[i];
        }
    }
    __syncthreads();

    // ---- phase 1: coalesced float4 reads of X, deposit 4 bits into row mask ----
    const int tileVec = ROWS_PER_BLOCK * DATA_BITS / 4;      // 3648
    const float4* Xv = (const float4*)X + (xBase >> 2);
    for (int i = t; i < tileVec; i += BLOCK) {
        if (xBase + (long long)i * 4 < totalX) {
            float4 f = Xv[i];
            uint32_t v = ((__float_as_uint(f.x) >> 23) & 1u)
                       | ((__float_as_uint(f.y) >> 23) & 1u) << 1
                       | ((__float_as_uint(f.z) >> 23) & 1u) << 2
                       | ((__float_as_uint(f.w) >> 23) & 1u) << 3;
            if (v) {
                int p   = i * 4;
                int row = p / DATA_BITS;            // const-div -> magic mul
                int col = p - row * DATA_BITS;
                uint32_t v1 = v, v2 = 0;
                int r2 = row;
                if (col > DATA_BITS - 4) {          // straddles row boundary
                    int len1 = DATA_BITS - col;
                    v1 = v & ((1u << len1) - 1u);
                    v2 = v >> len1;
                    r2 = row + 1;
                }
                uint64_t val = (uint64_t)v1 << col;
                if ((uint32_t)val)         atomicOr(&mlo[row], (uint32_t)val);
                if ((uint32_t)(val >> 32)) atomicOr(&mhi[row], (uint32_t)(val >> 32));
                if (v2)                    atomicOr(&mlo[r2], v2);   // col 0..2 of next row
            }
        }
    }
    __syncthreads();

    // ---- phase 2: per-row shift on the packed mask ----
    {
        const long long row = blockRow0 + t;
        if (row < batch) {
            uint64_t mask = ((uint64_t)mhi[t] << 32) | mlo[t];

            const float* sr = &stile[t * SHIFT_BITS];
            int s = 0;
            #pragma unroll
            for (int l = 0; l < SHIFT_BITS; ++l) {
                uint32_t u = __float_as_uint(sr[l]);
                s |= (int)((u >> 23) & 1u) << (SHIFT_BITS - 1 - l);
            }

            uint64_t outm = (mask << s) & ((1ULL << DATA_BITS) - 1ULL);
            uint64_t dropped = (s >= DATA_BITS) ? mask : (mask >> (DATA_BITS - s));
            outSticky[row] = (dropped != 0ULL) ? 1.0f : 0.0f;

            mlo[t] = (uint32_t)outm;
            mhi[t] = (uint32_t)(outm >> 32);
        }
    }
    __syncthreads();

    // ---- phase 3: expand out-masks back to 0/1 floats, coalesced float4 stores ----
    float4* Ov = (float4*)outCur + (xBase >> 2);
    for (int i = t; i < tileVec; i += BLOCK) {
        if (xBase + (long long)i * 4 < totalX) {
            int p   = i * 4;
            int row = p / DATA_BITS;
            int col = p - row * DATA_BITS;
            uint64_t m1 = ((uint64_t)mhi[row] << 32) | mlo[row];
            uint32_t chunk;
            if (col <= DATA_BITS - 4) {
                chunk = (uint32_t)(m1 >> col) & 0xFu;
            } else {
                int len1 = DATA_BITS - col;
                uint64_t m2 = ((uint64_t)mhi[row + 1] << 32) | mlo[row + 1];
                chunk = ((uint32_t)(m1 >> col) | ((uint32_t)m2 << len1)) & 0xFu;
            }
            float4 f;
            f.x = __uint_as_float((0u - (chunk        & 1u)) & 0x3F800000u);
            f.y = __uint_as_float((0u - ((chunk >> 1) & 1u)) & 0x3F800000u);
            f.z = __uint_as_float((0u - ((chunk >> 2) & 1u)) & 0x3F800000u);
            f.w = __uint_as_float((0u - ((chunk >> 3) & 1u)) & 0x3F800000u);
            Ov[i] = f;
        }
    }
}

extern "C" void kernel_launch(void* const* d_in, const int* in_sizes, int n_in,
                              void* d_out, int out_size, void* d_ws, size_t ws_size,
                              hipStream_t stream) {
    const float* X = (const float*)d_in[0];
    const float* S = (const float*)d_in[1];
    const int batch = in_sizes[1] / SHIFT_BITS;       // 1,000,000
    float* outCur = (float*)d_out;                    // batch*57 floats
    float* outSticky = outCur + (long long)batch * DATA_BITS;  // batch floats

    const int grid = (batch + ROWS_PER_BLOCK - 1) / ROWS_PER_BLOCK;
    barrel57_kernel<<<grid, BLOCK, 0, stream>>>(X, S, outCur, outSticky, batch);
}

// Round 3
// 76.055 us; speedup vs baseline: 1.7280x; 1.4281x over previous
//
#include <hip/hip_runtime.h>
#include <stdint.h>

#define DATA_BITS 57
#define SHIFT_BITS 6
#define ROWS_PER_BLOCK 256
#define BLOCK 256
#define TILE_VEC (ROWS_PER_BLOCK * DATA_BITS / 4)    // 3648 float4s per block tile
#define K_FULL (TILE_VEC / BLOCK)                    // 14 full passes
#define K_REM  (TILE_VEC - K_FULL * BLOCK)           // 64 extra (threads t<64)
#define STILE_VEC (ROWS_PER_BLOCK * SHIFT_BITS / 4)  // 384
#define MASK57 ((1ULL << DATA_BITS) - 1ULL)

typedef float floatx4 __attribute__((ext_vector_type(4)));

__device__ __forceinline__ void deposit(unsigned long long* masks, int p, float4 f) {
    uint32_t v = ((__float_as_uint(f.x) >> 23) & 1u)
               | (((__float_as_uint(f.y) >> 23) & 1u) << 1)
               | (((__float_as_uint(f.z) >> 23) & 1u) << 2)
               | (((__float_as_uint(f.w) >> 23) & 1u) << 3);
    if (v) {
        int row = p / DATA_BITS;               // magic-mul const div
        int col = p - row * DATA_BITS;         // 0..56
        unsigned long long val = (unsigned long long)v << col;  // fits in 64b (<= bit 59)
        atomicOr(&masks[row], val & MASK57);   // ds_or_b64
        unsigned long long spill = val >> DATA_BITS;  // bits for next row (rare)
        if (spill) atomicOr(&masks[row + 1], spill);
    }
}

__device__ __forceinline__ floatx4 expand(const unsigned long long* masks, int p) {
    int row = p / DATA_BITS;
    int col = p - row * DATA_BITS;
    unsigned long long m = masks[row] >> col;          // ds_read_b64
    if (col > DATA_BITS - 4)                           // ~5% of iters
        m |= masks[row + 1] << (DATA_BITS - col);
    uint32_t c = (uint32_t)m;
    floatx4 f;
    f.x = __uint_as_float((0u - (c        & 1u)) & 0x3F800000u);
    f.y = __uint_as_float((0u - ((c >> 1) & 1u)) & 0x3F800000u);
    f.z = __uint_as_float((0u - ((c >> 2) & 1u)) & 0x3F800000u);
    f.w = __uint_as_float((0u - ((c >> 3) & 1u)) & 0x3F800000u);
    return f;
}

__global__ __launch_bounds__(BLOCK, 4) void barrel57_kernel(
    const float* __restrict__ X, const float* __restrict__ S,
    float* __restrict__ outCur, float* __restrict__ outSticky,
    int batch)
{
    __shared__ unsigned long long masks[ROWS_PER_BLOCK + 1];  // 2056 B
    __shared__ float stile[ROWS_PER_BLOCK * SHIFT_BITS];      // 6 KB

    const int t = threadIdx.x;
    const long long blockRow0 = (long long)blockIdx.x * ROWS_PER_BLOCK;
    const long long xBase = blockRow0 * DATA_BITS;
    const long long sBase = blockRow0 * SHIFT_BITS;
    const bool fullBlock = (blockRow0 + ROWS_PER_BLOCK <= (long long)batch);

    masks[t] = 0ULL;
    if (t == 0) masks[ROWS_PER_BLOCK] = 0ULL;

    const float4* Xv = (const float4*)X + (xBase >> 2);
    const float4* Sv = (const float4*)S + (sBase >> 2);

    if (fullBlock) {
        // ---- issue ALL tile loads up front: 15 global_load_dwordx4 in flight ----
        float4 f[K_FULL];
        float4 fr;
        #pragma unroll
        for (int k = 0; k < K_FULL; ++k) f[k] = Xv[t + k * BLOCK];
        if (t < K_REM) fr = Xv[t + K_FULL * BLOCK];
        #pragma unroll
        for (int k = 0; k < 2; ++k) {                 // stile: 384 vecs
            int i = t + k * BLOCK;
            if (i < STILE_VEC) *(float4*)&stile[i * 4] = Sv[i];
        }
        __syncthreads();                              // masks zero-init visible
        #pragma unroll
        for (int k = 0; k < K_FULL; ++k) deposit(masks, (t + k * BLOCK) * 4, f[k]);
        if (t < K_REM) deposit(masks, (t + K_FULL * BLOCK) * 4, fr);
    } else {
        const long long totalX = (long long)batch * DATA_BITS;  // %4 == 0
        const long long totalS = (long long)batch * SHIFT_BITS; // %4 == 0
        for (int i = t; i < STILE_VEC; i += BLOCK)
            if (sBase + (long long)i * 4 < totalS) *(float4*)&stile[i * 4] = Sv[i];
        __syncthreads();
        for (int i = t; i < TILE_VEC; i += BLOCK)
            if (xBase + (long long)i * 4 < totalX) deposit(masks, i * 4, Xv[i]);
    }
    __syncthreads();

    // ---- phase 2: per-row shift on packed 57-bit mask ----
    {
        const long long row = blockRow0 + t;
        if (row < batch) {
            unsigned long long mask = masks[t];
            const float* sr = &stile[t * SHIFT_BITS];
            int s = 0;
            #pragma unroll
            for (int l = 0; l < SHIFT_BITS; ++l)
                s |= (int)((__float_as_uint(sr[l]) >> 23) & 1u) << (SHIFT_BITS - 1 - l);
            unsigned long long outm = (mask << s) & MASK57;
            unsigned long long dropped = (s >= DATA_BITS) ? mask : (mask >> (DATA_BITS - s));
            __builtin_nontemporal_store((dropped != 0ULL) ? 1.0f : 0.0f, &outSticky[row]);
            masks[t] = outm;
        }
    }
    __syncthreads();

    // ---- phase 3: expand masks -> 0/1 floats, coalesced nontemporal float4 stores ----
    floatx4* Ov = (floatx4*)outCur + (xBase >> 2);
    if (fullBlock) {
        #pragma unroll
        for (int k = 0; k < K_FULL; ++k) {
            int i = t + k * BLOCK;
            __builtin_nontemporal_store(expand(masks, i * 4), &Ov[i]);
        }
        if (t < K_REM) {
            int i = t + K_FULL * BLOCK;
            __builtin_nontemporal_store(expand(masks, i * 4), &Ov[i]);
        }
    } else {
        const long long totalX = (long long)batch * DATA_BITS;
        for (int i = t; i < TILE_VEC; i += BLOCK)
            if (xBase + (long long)i * 4 < totalX)
                __builtin_nontemporal_store(expand(masks, i * 4), &Ov[i]);
    }
}

extern "C" void kernel_launch(void* const* d_in, const int* in_sizes, int n_in,
                              void* d_out, int out_size, void* d_ws, size_t ws_size,
                              hipStream_t stream) {
    const float* X = (const float*)d_in[0];
    const float* S = (const float*)d_in[1];
    const int batch = in_sizes[1] / SHIFT_BITS;       // 1,000,000
    float* outCur = (float*)d_out;                    // batch*57 floats
    float* outSticky = outCur + (long long)batch * DATA_BITS;  // batch floats

    const int grid = (batch + ROWS_PER_BLOCK - 1) / ROWS_PER_BLOCK;
    barrel57_kernel<<<grid, BLOCK, 0, stream>>>(X, S, outCur, outSticky, batch);
}